// Round 5
// baseline (87.254 us; speedup 1.0000x reference)
//
#include <hip/hip_runtime.h>
#include <cstdint>

// Problem geometry: x (16,64,64,64) f32 -> out (16,32,32,32,4) f32
#define NSITES (16 * 32 * 32 * 32)   // 524288 sites, out_size = NSITES*4

struct GateOp { int type; int a; int b; int widx; };  // type 0: rot(kind=a, wire=b, theta=params[widx]); type 1: cnot(ctrl=a, tgt=b)
struct OpList { int n; GateOp ops[24]; };

// ---------------- device: 4-qubit statevector simulator ----------------
// State layout: flat index t = a*8+b*4+c*2+d, wire w <-> bitmask (8 >> w).

template <int MASK>
__device__ __forceinline__ void rot_pairs(int kind, float c, float s, float re[16], float im[16]) {
#pragma unroll
  for (int t = 0; t < 16; t++) {
    if (t & MASK) continue;
    const int u = t | MASK;
    float r0 = re[t], i0 = im[t], r1 = re[u], i1 = im[u];
    if (kind == 0) {          // RX: [[c,-is],[-is,c]]
      re[t] = fmaf(c, r0,  s * i1);  im[t] = fmaf(c, i0, -s * r1);
      re[u] = fmaf(s, i0,  c * r1);  im[u] = fmaf(-s, r0, c * i1);
    } else if (kind == 1) {   // RY: [[c,-s],[s,c]]
      re[t] = fmaf(c, r0, -s * r1);  im[t] = fmaf(c, i0, -s * i1);
      re[u] = fmaf(s, r0,  c * r1);  im[u] = fmaf(s, i0,  c * i1);
    } else {                  // RZ: diag(e^{-i th/2}, e^{+i th/2})
      re[t] = fmaf(c, r0,  s * i0);  im[t] = fmaf(c, i0, -s * r0);
      re[u] = fmaf(c, r1, -s * i1);  im[u] = fmaf(c, i1,  s * r1);
    }
  }
}

template <int CM, int TM>
__device__ __forceinline__ void cnot_pairs(float re[16], float im[16]) {
#pragma unroll
  for (int t = 0; t < 16; t++) {
    if ((t & CM) && !(t & TM)) {
      const int u = t | TM;
      float tr = re[t]; re[t] = re[u]; re[u] = tr;
      float ti = im[t]; im[t] = im[u]; im[u] = ti;
    }
  }
}

__device__ __forceinline__ void init_state(float p0, float p1, float p2, float p3,
                                           float re[16], float im[16]) {
  const float HALF_PI = 1.57079632679489662f;
  float cw[4], sw[4];
  __sincosf(HALF_PI * p0, &sw[0], &cw[0]);
  __sincosf(HALF_PI * p1, &sw[1], &cw[1]);
  __sincosf(HALF_PI * p2, &sw[2], &cw[2]);
  __sincosf(HALF_PI * p3, &sw[3], &cw[3]);
#pragma unroll
  for (int t = 0; t < 16; t++) {
    float v = ((t & 8) ? sw[0] : cw[0]) * ((t & 4) ? sw[1] : cw[1]);
    v *= ((t & 2) ? sw[2] : cw[2]) * ((t & 1) ? sw[3] : cw[3]);
    re[t] = v; im[t] = 0.f;
  }
}

__device__ __forceinline__ float4 readout(const float re[16], const float im[16]) {
  float z0 = 0.f, z1 = 0.f, z2 = 0.f, z3 = 0.f;
#pragma unroll
  for (int t = 0; t < 16; t++) {
    float p = re[t] * re[t] + im[t] * im[t];
    z0 += (t & 8) ? -p : p;
    z1 += (t & 4) ? -p : p;
    z2 += (t & 2) ? -p : p;
    z3 += (t & 1) ? -p : p;
  }
  return make_float4(z0, z1, z2, z3);
}

// Two k-adjacent sites per thread: fully-coalesced dwordx4 loads, gate
// interpreter (wave-uniform branches) amortized over both sites.
__global__ __launch_bounds__(256) void quanv_kernel(
    const float* __restrict__ x, const float* __restrict__ params,
    float* __restrict__ out, OpList ol) {
  int n = blockIdx.x * blockDim.x + threadIdx.x;   // n in [0, NSITES/2)
  int m = n & 15, j = (n >> 4) & 31, i = (n >> 9) & 31, b = n >> 14;
  const float* xb = x + (size_t)b * 262144;  // 64*64*64
  int i2 = 2 * i, j2 = 2 * j;
  // rows (256B each); float4 at element offset 4m covers input k = 4m..4m+3
  const float4* r00 = reinterpret_cast<const float4*>(xb + (i2    ) * 4096 + (j2    ) * 64);
  const float4* r11 = reinterpret_cast<const float4*>(xb + (i2 + 1) * 4096 + (j2 + 1) * 64);
  const float4* r01 = reinterpret_cast<const float4*>(xb + (i2    ) * 4096 + (j2 + 1) * 64);
  const float4* r10 = reinterpret_cast<const float4*>(xb + (i2 + 1) * 4096 + (j2    ) * 64);
  float4 f0 = r00[m];   // phi0: even k -> .x (site A), .z (site B)
  float4 f1 = r11[m];   // phi1: even k
  float4 f2 = r01[m];   // phi2: odd k  -> .y (site A), .w (site B)
  float4 f3 = r10[m];   // phi3: odd k

  float reA[16], imA[16], reB[16], imB[16];
  init_state(f0.x, f1.x, f2.y, f3.y, reA, imA);
  init_state(f0.z, f1.z, f2.w, f3.w, reB, imB);

  for (int g = 0; g < ol.n; g++) {
    GateOp op = ol.ops[g];
    if (op.type == 0) {
      float theta = params[op.widx];
      float c, s;
      __sincosf(0.5f * theta, &s, &c);
      switch (op.b) {
        case 0:  rot_pairs<8>(op.a, c, s, reA, imA); rot_pairs<8>(op.a, c, s, reB, imB); break;
        case 1:  rot_pairs<4>(op.a, c, s, reA, imA); rot_pairs<4>(op.a, c, s, reB, imB); break;
        case 2:  rot_pairs<2>(op.a, c, s, reA, imA); rot_pairs<2>(op.a, c, s, reB, imB); break;
        default: rot_pairs<1>(op.a, c, s, reA, imA); rot_pairs<1>(op.a, c, s, reB, imB); break;
      }
    } else {
      switch (op.a * 4 + op.b) {
        case 1:  cnot_pairs<8, 4>(reA, imA); cnot_pairs<8, 4>(reB, imB); break;
        case 2:  cnot_pairs<8, 2>(reA, imA); cnot_pairs<8, 2>(reB, imB); break;
        case 3:  cnot_pairs<8, 1>(reA, imA); cnot_pairs<8, 1>(reB, imB); break;
        case 4:  cnot_pairs<4, 8>(reA, imA); cnot_pairs<4, 8>(reB, imB); break;
        case 6:  cnot_pairs<4, 2>(reA, imA); cnot_pairs<4, 2>(reB, imB); break;
        case 7:  cnot_pairs<4, 1>(reA, imA); cnot_pairs<4, 1>(reB, imB); break;
        case 8:  cnot_pairs<2, 8>(reA, imA); cnot_pairs<2, 8>(reB, imB); break;
        case 9:  cnot_pairs<2, 4>(reA, imA); cnot_pairs<2, 4>(reB, imB); break;
        case 11: cnot_pairs<2, 1>(reA, imA); cnot_pairs<2, 1>(reB, imB); break;
        case 12: cnot_pairs<1, 8>(reA, imA); cnot_pairs<1, 8>(reB, imB); break;
        case 13: cnot_pairs<1, 4>(reA, imA); cnot_pairs<1, 4>(reB, imB); break;
        case 14: cnot_pairs<1, 2>(reA, imA); cnot_pairs<1, 2>(reB, imB); break;
      }
    }
  }

  float4* out4 = reinterpret_cast<float4*>(out);
  out4[2 * n]     = readout(reA, imA);   // site k = 2m
  out4[2 * n + 1] = readout(reB, imB);   // site k = 2m+1
}

// ---------------- host: bit-exact numpy default_rng(42) op-list replication ----------------
// VERIFIED in round 4 (absmax 3.9e-3). Key subtlety: SeedSequence mix() is
// (x*MIX_MULT_L - y*MIX_MULT_R), subtraction per O'Neill seed_seq_fe.
// Routing: random() -> next64>>11 * 2^-53; integers() -> bounded_lemire_uint32
// on buffered next32 (low half first); shuffle -> random_interval masked rejection.

typedef unsigned __int128 u128;

static void build_ops(OpList& ol) {
  // SeedSequence(42): pool mixing
  uint32_t pool[4];
  {
    uint32_t hc = 0x43b0d7e5u;                    // INIT_A
    auto hashmix = [&hc](uint32_t value) -> uint32_t {
      value ^= hc;
      hc *= 0x931e8875u;                          // MULT_A
      value *= hc;
      value ^= value >> 16;
      return value;
    };
    auto mix = [](uint32_t xx, uint32_t yy) -> uint32_t {
      uint32_t r = xx * 0xca01f9ddu - yy * 0x4973f715u;  // MIX_MULT_L*x - MIX_MULT_R*y
      r ^= r >> 16;
      return r;
    };
    uint32_t entropy0 = 42u;
    for (int ii = 0; ii < 4; ii++) pool[ii] = hashmix(ii < 1 ? entropy0 : 0u);
    for (int src = 0; src < 4; src++)
      for (int dst = 0; dst < 4; dst++)
        if (src != dst) {
          uint32_t h = hashmix(pool[src]);
          pool[dst] = mix(pool[dst], h);
        }
  }
  // generate_state(4, uint64): 8 uint32 words -> 4 uint64 (little-endian pairs)
  uint64_t val[4];
  {
    uint32_t hc = 0x8b51f9ddu;                    // INIT_B
    uint32_t w32[8];
    for (int ii = 0; ii < 8; ii++) {
      uint32_t dv = pool[ii & 3];
      dv ^= hc;
      hc *= 0x58f38dedu;                          // MULT_B
      dv *= hc;
      dv ^= dv >> 16;
      w32[ii] = dv;
    }
    for (int kk = 0; kk < 4; kk++)
      val[kk] = (uint64_t)w32[2 * kk] | ((uint64_t)w32[2 * kk + 1] << 32);
  }
  // PCG64 (setseq 128 XSL-RR 64): initstate = (val0<<64)|val1, initseq = (val2<<64)|val3
  const u128 MULT = ((u128)2549297995355413924ULL << 64) | (u128)4865540595714422341ULL;
  u128 state, inc;
  {
    u128 initstate = ((u128)val[0] << 64) | (u128)val[1];
    u128 initseq = ((u128)val[2] << 64) | (u128)val[3];
    inc = (initseq << 1) | (u128)1;
    state = 0;
    state = state * MULT + inc;   // step
    state += initstate;
    state = state * MULT + inc;   // step
  }
  bool has32 = false;
  uint32_t buf32 = 0;
  auto next64 = [&]() -> uint64_t {
    state = state * MULT + inc;   // step-then-output (128-bit setseq variant)
    uint64_t hi = (uint64_t)(state >> 64), lo = (uint64_t)state;
    uint64_t xv = hi ^ lo;
    unsigned rot = (unsigned)(state >> 122) & 63u;
    return (xv >> rot) | (xv << ((64u - rot) & 63u));
  };
  auto next32 = [&]() -> uint32_t {
    if (has32) { has32 = false; return buf32; }
    uint64_t nn = next64();
    has32 = true;
    buf32 = (uint32_t)(nn >> 32);
    return (uint32_t)nn;
  };
  auto nextDouble = [&]() -> double {
    return (double)(next64() >> 11) * (1.0 / 9007199254740992.0);
  };
  auto lemire32 = [&](uint32_t rng) -> uint32_t {  // integers(): uniform on [0, rng] inclusive
    const uint32_t rng_excl = rng + 1u;
    uint64_t m = (uint64_t)next32() * (uint64_t)rng_excl;
    uint32_t leftover = (uint32_t)m;
    if (leftover < rng_excl) {
      const uint32_t threshold = (uint32_t)((0xFFFFFFFFu - rng) % rng_excl);
      while (leftover < threshold) {
        m = (uint64_t)next32() * (uint64_t)rng_excl;
        leftover = (uint32_t)m;
      }
    }
    return (uint32_t)(m >> 32);
  };
  auto random_interval = [&](uint32_t mx) -> uint32_t {  // shuffle(): masked rejection
    if (mx == 0) return 0;
    uint32_t mask = mx;
    mask |= mask >> 1; mask |= mask >> 2; mask |= mask >> 4;
    mask |= mask >> 8; mask |= mask >> 16;
    uint32_t value;
    while ((value = (next32() & mask)) > mx) { }
    return value;
  };

  // _random_layer_ops: weights_shape=(1,4), wires=4, ratio_imprim=0.3
  ol.n = 0;
  int guard = 0;
  for (int l = 0; l < 1; l++) {
    int i = 0;
    while (i < 4 && guard < 1000000) {
      guard++;
      if (nextDouble() > 0.3) {
        int kind = (int)lemire32(2u);  // integers(0,3)
        int wq = (int)lemire32(3u);    // integers(0,4)
        if (ol.n < 24) { ol.ops[ol.n] = GateOp{0, kind, wq, l * 4 + i}; ol.n++; }
        i++;
      } else {
        int arr[4] = {0, 1, 2, 3};     // permutation(4): Fisher-Yates, i = 3..1
        for (int t = 3; t >= 1; t--) {
          int jj = (int)random_interval((uint32_t)t);
          int tmp = arr[t]; arr[t] = arr[jj]; arr[jj] = tmp;
        }
        if (ol.n < 24) { ol.ops[ol.n] = GateOp{1, arr[0], arr[1], 0}; ol.n++; }
      }
    }
  }
}

extern "C" void kernel_launch(void* const* d_in, const int* in_sizes, int n_in,
                              void* d_out, int out_size, void* d_ws, size_t ws_size,
                              hipStream_t stream) {
  const float* x = (const float*)d_in[0];
  const float* rp = (const float*)d_in[1];
  float* out = (float*)d_out;

  OpList ol;
  build_ops(ol);  // deterministic: identical every call (graph-capture safe)

  dim3 grid(NSITES / 2 / 256), block(256);   // 2 sites per thread
  hipLaunchKernelGGL(quanv_kernel, grid, block, 0, stream, x, rp, out, ol);
}

// Round 6
// 81.021 us; speedup vs baseline: 1.0769x; 1.0769x over previous
//
#include <hip/hip_runtime.h>
#include <cstdint>

// Problem geometry: x (16,64,64,64) f32 -> out (16,32,32,32,4) f32
// Kernel floor: fetch 16.8 MB + write 8.4 MB ~= 4 us @ 6.3 TB/s; VALU ~= 4 us.
#define NSITES (16 * 32 * 32 * 32)   // 524288 sites, out_size = NSITES*4

struct GateOp { int type; int a; int b; int widx; };  // type 0: rot(kind=a, wire=b, theta=params[widx]); type 1: cnot(ctrl=a, tgt=b)
struct OpList { int n; GateOp ops[24]; };

// ---------------- device: 4-qubit statevector simulator ----------------
// State layout: flat index t = a*8+b*4+c*2+d, wire w <-> bitmask (8 >> w).

template <int MASK>
__device__ __forceinline__ void rot_pairs(int kind, float c, float s, float re[16], float im[16]) {
#pragma unroll
  for (int t = 0; t < 16; t++) {
    if (t & MASK) continue;
    const int u = t | MASK;
    float r0 = re[t], i0 = im[t], r1 = re[u], i1 = im[u];
    if (kind == 0) {          // RX: [[c,-is],[-is,c]]
      re[t] = fmaf(c, r0,  s * i1);  im[t] = fmaf(c, i0, -s * r1);
      re[u] = fmaf(s, i0,  c * r1);  im[u] = fmaf(-s, r0, c * i1);
    } else if (kind == 1) {   // RY: [[c,-s],[s,c]]
      re[t] = fmaf(c, r0, -s * r1);  im[t] = fmaf(c, i0, -s * i1);
      re[u] = fmaf(s, r0,  c * r1);  im[u] = fmaf(s, i0,  c * i1);
    } else {                  // RZ: diag(e^{-i th/2}, e^{+i th/2})
      re[t] = fmaf(c, r0,  s * i0);  im[t] = fmaf(c, i0, -s * r0);
      re[u] = fmaf(c, r1, -s * i1);  im[u] = fmaf(c, i1,  s * r1);
    }
  }
}

template <int CM, int TM>
__device__ __forceinline__ void cnot_pairs(float re[16], float im[16]) {
#pragma unroll
  for (int t = 0; t < 16; t++) {
    if ((t & CM) && !(t & TM)) {
      const int u = t | TM;
      float tr = re[t]; re[t] = re[u]; re[u] = tr;
      float ti = im[t]; im[t] = im[u]; im[u] = ti;
    }
  }
}

// One site per thread; float2 row loads (perfectly coalesced: 32 consecutive
// lanes cover a full 256B row). Site k uses .x (even elem 2k) of rows
// (2i,2j),(2i+1,2j+1) and .y (odd elem 2k+1) of rows (2i,2j+1),(2i+1,2j).
__global__ __launch_bounds__(256) void quanv_kernel(
    const float* __restrict__ x, const float* __restrict__ params,
    float* __restrict__ out, OpList ol) {
  int n = blockIdx.x * blockDim.x + threadIdx.x;
  int k = n & 31, j = (n >> 5) & 31, i = (n >> 10) & 31, b = n >> 15;
  const float* xb = x + (size_t)b * 262144;  // 64*64*64
  int i2 = 2 * i, j2 = 2 * j;
  const float2* r00 = reinterpret_cast<const float2*>(xb + (i2    ) * 4096 + (j2    ) * 64);
  const float2* r11 = reinterpret_cast<const float2*>(xb + (i2 + 1) * 4096 + (j2 + 1) * 64);
  const float2* r01 = reinterpret_cast<const float2*>(xb + (i2    ) * 4096 + (j2 + 1) * 64);
  const float2* r10 = reinterpret_cast<const float2*>(xb + (i2 + 1) * 4096 + (j2    ) * 64);
  float2 f0 = r00[k];   // phi0 = .x
  float2 f1 = r11[k];   // phi1 = .x
  float2 f2 = r01[k];   // phi2 = .y
  float2 f3 = r10[k];   // phi3 = .y

  const float HALF_PI = 1.57079632679489662f;
  float cw[4], sw[4];
  __sincosf(HALF_PI * f0.x, &sw[0], &cw[0]);
  __sincosf(HALF_PI * f1.x, &sw[1], &cw[1]);
  __sincosf(HALF_PI * f2.y, &sw[2], &cw[2]);
  __sincosf(HALF_PI * f3.y, &sw[3], &cw[3]);

  float re[16], im[16];
#pragma unroll
  for (int t = 0; t < 16; t++) {
    float v = ((t & 8) ? sw[0] : cw[0]) * ((t & 4) ? sw[1] : cw[1]);
    v *= ((t & 2) ? sw[2] : cw[2]) * ((t & 1) ? sw[3] : cw[3]);
    re[t] = v; im[t] = 0.f;
  }

  for (int g = 0; g < ol.n; g++) {
    GateOp op = ol.ops[g];
    if (op.type == 0) {
      float theta = params[op.widx];
      float c, s;
      __sincosf(0.5f * theta, &s, &c);
      switch (op.b) {
        case 0:  rot_pairs<8>(op.a, c, s, re, im); break;
        case 1:  rot_pairs<4>(op.a, c, s, re, im); break;
        case 2:  rot_pairs<2>(op.a, c, s, re, im); break;
        default: rot_pairs<1>(op.a, c, s, re, im); break;
      }
    } else {
      switch (op.a * 4 + op.b) {
        case 1:  cnot_pairs<8, 4>(re, im); break;
        case 2:  cnot_pairs<8, 2>(re, im); break;
        case 3:  cnot_pairs<8, 1>(re, im); break;
        case 4:  cnot_pairs<4, 8>(re, im); break;
        case 6:  cnot_pairs<4, 2>(re, im); break;
        case 7:  cnot_pairs<4, 1>(re, im); break;
        case 8:  cnot_pairs<2, 8>(re, im); break;
        case 9:  cnot_pairs<2, 4>(re, im); break;
        case 11: cnot_pairs<2, 1>(re, im); break;
        case 12: cnot_pairs<1, 8>(re, im); break;
        case 13: cnot_pairs<1, 4>(re, im); break;
        case 14: cnot_pairs<1, 2>(re, im); break;
      }
    }
  }

  float z0 = 0.f, z1 = 0.f, z2 = 0.f, z3 = 0.f;
#pragma unroll
  for (int t = 0; t < 16; t++) {
    float p = re[t] * re[t] + im[t] * im[t];
    z0 += (t & 8) ? -p : p;
    z1 += (t & 4) ? -p : p;
    z2 += (t & 2) ? -p : p;
    z3 += (t & 1) ? -p : p;
  }
  reinterpret_cast<float4*>(out)[n] = make_float4(z0, z1, z2, z3);
}

// ---------------- host: bit-exact numpy default_rng(42) op-list replication ----------------
// VERIFIED round 4 (absmax 3.9e-3). Key subtlety: SeedSequence mix() is
// (x*MIX_MULT_L - y*MIX_MULT_R), subtraction per O'Neill seed_seq_fe.
// Routing: random() -> next64>>11 * 2^-53; integers() -> bounded_lemire_uint32
// on buffered next32 (low half first); shuffle -> random_interval masked rejection.

typedef unsigned __int128 u128;

static void build_ops(OpList& ol) {
  // SeedSequence(42): pool mixing
  uint32_t pool[4];
  {
    uint32_t hc = 0x43b0d7e5u;                    // INIT_A
    auto hashmix = [&hc](uint32_t value) -> uint32_t {
      value ^= hc;
      hc *= 0x931e8875u;                          // MULT_A
      value *= hc;
      value ^= value >> 16;
      return value;
    };
    auto mix = [](uint32_t xx, uint32_t yy) -> uint32_t {
      uint32_t r = xx * 0xca01f9ddu - yy * 0x4973f715u;  // MIX_MULT_L*x - MIX_MULT_R*y
      r ^= r >> 16;
      return r;
    };
    uint32_t entropy0 = 42u;
    for (int ii = 0; ii < 4; ii++) pool[ii] = hashmix(ii < 1 ? entropy0 : 0u);
    for (int src = 0; src < 4; src++)
      for (int dst = 0; dst < 4; dst++)
        if (src != dst) {
          uint32_t h = hashmix(pool[src]);
          pool[dst] = mix(pool[dst], h);
        }
  }
  // generate_state(4, uint64): 8 uint32 words -> 4 uint64 (little-endian pairs)
  uint64_t val[4];
  {
    uint32_t hc = 0x8b51f9ddu;                    // INIT_B
    uint32_t w32[8];
    for (int ii = 0; ii < 8; ii++) {
      uint32_t dv = pool[ii & 3];
      dv ^= hc;
      hc *= 0x58f38dedu;                          // MULT_B
      dv *= hc;
      dv ^= dv >> 16;
      w32[ii] = dv;
    }
    for (int kk = 0; kk < 4; kk++)
      val[kk] = (uint64_t)w32[2 * kk] | ((uint64_t)w32[2 * kk + 1] << 32);
  }
  // PCG64 (setseq 128 XSL-RR 64): initstate = (val0<<64)|val1, initseq = (val2<<64)|val3
  const u128 MULT = ((u128)2549297995355413924ULL << 64) | (u128)4865540595714422341ULL;
  u128 state, inc;
  {
    u128 initstate = ((u128)val[0] << 64) | (u128)val[1];
    u128 initseq = ((u128)val[2] << 64) | (u128)val[3];
    inc = (initseq << 1) | (u128)1;
    state = 0;
    state = state * MULT + inc;   // step
    state += initstate;
    state = state * MULT + inc;   // step
  }
  bool has32 = false;
  uint32_t buf32 = 0;
  auto next64 = [&]() -> uint64_t {
    state = state * MULT + inc;   // step-then-output (128-bit setseq variant)
    uint64_t hi = (uint64_t)(state >> 64), lo = (uint64_t)state;
    uint64_t xv = hi ^ lo;
    unsigned rot = (unsigned)(state >> 122) & 63u;
    return (xv >> rot) | (xv << ((64u - rot) & 63u));
  };
  auto next32 = [&]() -> uint32_t {
    if (has32) { has32 = false; return buf32; }
    uint64_t nn = next64();
    has32 = true;
    buf32 = (uint32_t)(nn >> 32);
    return (uint32_t)nn;
  };
  auto nextDouble = [&]() -> double {
    return (double)(next64() >> 11) * (1.0 / 9007199254740992.0);
  };
  auto lemire32 = [&](uint32_t rng) -> uint32_t {  // integers(): uniform on [0, rng] inclusive
    const uint32_t rng_excl = rng + 1u;
    uint64_t m = (uint64_t)next32() * (uint64_t)rng_excl;
    uint32_t leftover = (uint32_t)m;
    if (leftover < rng_excl) {
      const uint32_t threshold = (uint32_t)((0xFFFFFFFFu - rng) % rng_excl);
      while (leftover < threshold) {
        m = (uint64_t)next32() * (uint64_t)rng_excl;
        leftover = (uint32_t)m;
      }
    }
    return (uint32_t)(m >> 32);
  };
  auto random_interval = [&](uint32_t mx) -> uint32_t {  // shuffle(): masked rejection
    if (mx == 0) return 0;
    uint32_t mask = mx;
    mask |= mask >> 1; mask |= mask >> 2; mask |= mask >> 4;
    mask |= mask >> 8; mask |= mask >> 16;
    uint32_t value;
    while ((value = (next32() & mask)) > mx) { }
    return value;
  };

  // _random_layer_ops: weights_shape=(1,4), wires=4, ratio_imprim=0.3
  ol.n = 0;
  int guard = 0;
  for (int l = 0; l < 1; l++) {
    int i = 0;
    while (i < 4 && guard < 1000000) {
      guard++;
      if (nextDouble() > 0.3) {
        int kind = (int)lemire32(2u);  // integers(0,3)
        int wq = (int)lemire32(3u);    // integers(0,4)
        if (ol.n < 24) { ol.ops[ol.n] = GateOp{0, kind, wq, l * 4 + i}; ol.n++; }
        i++;
      } else {
        int arr[4] = {0, 1, 2, 3};     // permutation(4): Fisher-Yates, i = 3..1
        for (int t = 3; t >= 1; t--) {
          int jj = (int)random_interval((uint32_t)t);
          int tmp = arr[t]; arr[t] = arr[jj]; arr[jj] = tmp;
        }
        if (ol.n < 24) { ol.ops[ol.n] = GateOp{1, arr[0], arr[1], 0}; ol.n++; }
      }
    }
  }
}

extern "C" void kernel_launch(void* const* d_in, const int* in_sizes, int n_in,
                              void* d_out, int out_size, void* d_ws, size_t ws_size,
                              hipStream_t stream) {
  const float* x = (const float*)d_in[0];
  const float* rp = (const float*)d_in[1];
  float* out = (float*)d_out;

  OpList ol;
  build_ops(ol);  // deterministic: identical every call (graph-capture safe)

  dim3 grid(NSITES / 256), block(256);   // 1 site per thread
  hipLaunchKernelGGL(quanv_kernel, grid, block, 0, stream, x, rp, out, ol);
}